// Round 17
// baseline (155.848 us; speedup 1.0000x reference)
//
#include <hip/hip_runtime.h>
#include <hip/hip_bf16.h>

// LFQ argmax, round 31: RESUBMIT of r30 (infra failure, no data).
// "MI355X container failed twice" = broker-level acquire failure, no
// pytest trace/dispatch record -> the r30 experiment never ran. Bounds
// re-check: worst over-read (split 7, pair 65) = ~4.21MB < cbs+sb1 extent,
// lands in mapped sb1, read-only -> safe. Resubmitting unchanged per
// single-variable discipline.
// r30 theory: with 2 pinned sets the issue->wait margin is ~600cyc (1
// COMPUTE): covers L2 (~200cyc) but not the ~8.5% L3/HBM misses
// (500-900cyc; FETCH 35MB vs 12MB ideal = cbs re-fetch). Third set qc
// (vmcnt(16)) doubles cover to ~1200cyc. Regs ~180 < 256 at 2 waves/SIMD.
// Validity: VGPR ~150-190. Canaries: FETCH ~35MB / WRITE ~2MB / absmax=0.
// Numerics unchanged (validated r15-r28): 1-term bf16 screen, 7-bit j-pack
// top-2 per split, MARGIN 0.4 exact rescore.
#define NT 16384
#define ND 128
#define NC 16384
#define NSPLIT 8
#define MARGIN 0.4f       // >= 3x worst pairwise 1-term bf16 comparison error

typedef __bf16 bf16x8 __attribute__((ext_vector_type(8)));
typedef unsigned short u16x8 __attribute__((ext_vector_type(8)));
typedef int i32x4 __attribute__((ext_vector_type(4)));
typedef float f32x4 __attribute__((ext_vector_type(4)));

#define MF __builtin_amdgcn_mfma_f32_16x16x32_bf16
#define B8(Q) __builtin_bit_cast(bf16x8, Q)

static __device__ __forceinline__ unsigned short f2bf(float f) {
    unsigned u = __float_as_uint(f);
    return (unsigned short)((u + 0x7FFFu + ((u >> 16) & 1u)) >> 16);
}
static __device__ __forceinline__ bf16x8 u2b(u16x8 u) {
    return __builtin_bit_cast(bf16x8, u);
}

// ---- codebook fp32 -> bf16 hi, fragment-coalesced image (r22 layout) ----
__global__ __launch_bounds__(256) void lfq_convert_cb(
    const float4* __restrict__ cb4, unsigned short* __restrict__ cbs)
{
    const unsigned i = blockIdx.x * 256 + threadIdx.x;   // 0..262143
    const unsigned c  = i >> 4;          // code 0..16383
    const unsigned k8 = i & 15u;         // dim chunk (d0 = k8*8)
    const float4 v0 = cb4[i * 2];
    const float4 v1 = cb4[i * 2 + 1];
    const unsigned split = c >> 11;
    const unsigned cl    = c & 2047u;
    const unsigned pair  = cl >> 5;
    const unsigned sp    = (cl >> 4) & 1u;
    const unsigned n     = cl & 15u;
    const unsigned k     = k8 >> 2;
    const unsigned quad  = k8 & 3u;
    const unsigned idx = split * 262144u + pair * 4096u + sp * 2048u +
                         k * 512u + quad * 128u + n * 8u;
    u16x8 h;
    h[0] = f2bf(v0.x); h[1] = f2bf(v0.y); h[2] = f2bf(v0.z); h[3] = f2bf(v0.w);
    h[4] = f2bf(v1.x); h[5] = f2bf(v1.y); h[6] = f2bf(v1.z); h[7] = f2bf(v1.w);
    *(u16x8*)(cbs + idx) = h;
}

// exact fp32 dot, register-preloaded x (fallback kernel)
static __device__ __forceinline__ float exact_dot(
    const float4* __restrict__ xr4, const float* __restrict__ cf, int cidx)
{
    const float4* cr = (const float4*)(cf + (size_t)cidx * ND);
    float a0 = 0.f, a1 = 0.f, a2 = 0.f, a3 = 0.f;
#pragma unroll
    for (int i = 0; i < 32; i += 4) {
        float4 x0 = xr4[i+0], x1 = xr4[i+1], x2 = xr4[i+2], x3 = xr4[i+3];
        float4 c0 = cr[i+0],  c1 = cr[i+1],  c2 = cr[i+2],  c3 = cr[i+3];
        a0 += x0.x*c0.x + x0.y*c0.y + x0.z*c0.z + x0.w*c0.w;
        a1 += x1.x*c1.x + x1.y*c1.y + x1.z*c1.z + x1.w*c1.w;
        a2 += x2.x*c2.x + x2.y*c2.y + x2.z*c2.z + x2.w*c2.w;
        a3 += x3.x*c3.x + x3.y*c3.y + x3.z*c3.z + x3.w*c3.w;
    }
    return (a0 + a1) + (a2 + a3);
}

// exact fp32 dot, both operands from global (combine kernel)
static __device__ __forceinline__ float exact_dot_g(
    const float* __restrict__ xf, const float* __restrict__ cf,
    int token, int cidx)
{
    const float4* xr = (const float4*)(xf + (size_t)token * ND);
    const float4* cr = (const float4*)(cf + (size_t)cidx * ND);
    float a0 = 0.f, a1 = 0.f, a2 = 0.f, a3 = 0.f;
#pragma unroll
    for (int i = 0; i < 32; i += 4) {
        float4 x0 = xr[i+0], x1 = xr[i+1], x2 = xr[i+2], x3 = xr[i+3];
        float4 c0 = cr[i+0], c1 = cr[i+1], c2 = cr[i+2], c3 = cr[i+3];
        a0 += x0.x*c0.x + x0.y*c0.y + x0.z*c0.z + x0.w*c0.w;
        a1 += x1.x*c1.x + x1.y*c1.y + x1.z*c1.z + x1.w*c1.w;
        a2 += x2.x*c2.x + x2.y*c2.y + x2.z*c2.z + x2.w*c2.w;
        a3 += x3.x*c3.x + x3.y*c3.y + x3.z*c3.z + x3.w*c3.w;
    }
    return (a0 + a1) + (a2 + a3);
}

static __device__ __forceinline__ void top2_upd(
    const f32x4& a, float* b1r, float* b2r, unsigned pk)
{
#pragma unroll
    for (int r4 = 0; r4 < 4; ++r4) {
        float p = __uint_as_float((__float_as_uint(a[r4]) & 0xFFFFFF80u) | pk);
        b2r[r4] = __builtin_amdgcn_fmed3f(p, b1r[r4], b2r[r4]);
        b1r[r4] = fmaxf(p, b1r[r4]);
    }
}

// ---- stage 1: grid 512 = 64 token-blocks(256 tok) x 8 splits ----
// Block: 256 threads = 4 waves; wave w covers tokens t0+w*64..+63 (tt=4).
// B fragments: asm-pinned global loads, 3 register sets, 2 pairs in
// flight (vmcnt(16)). No LDS, no barriers.
__global__ __launch_bounds__(256)
__attribute__((amdgpu_waves_per_eu(2, 2)))
void lfq_stage1(
    const float* __restrict__ xf, const unsigned short* __restrict__ cbs,
    float* __restrict__ sb1, float* __restrict__ sb2,
    int* __restrict__ si1, int* __restrict__ si2)
{
    const int split = blockIdx.x & 7;
    const int tb    = blockIdx.x >> 3;
    const int t0    = tb * 256;
    const int tid   = threadIdx.x;
    const int w     = tid >> 6;       // wave id = token-group, 0..3
    const int lane  = tid & 63;
    const int n     = lane & 15;
    const int quad  = lane >> 4;

    // A fragments: tokens t0 + w*64 + tt*16 + n, tt=0..3; fp32 -> bf16 (RN).
    bf16x8 ah[4][4];
#pragma unroll
    for (int tt = 0; tt < 4; ++tt) {
        const float* xr = xf + (size_t)(t0 + w * 64 + tt * 16 + n) * ND + quad * 8;
#pragma unroll
        for (int kk = 0; kk < 4; ++kk) {
            float4 v0 = *(const float4*)(xr + kk * 32);
            float4 v1 = *(const float4*)(xr + kk * 32 + 4);
            u16x8 hu;
            hu[0] = f2bf(v0.x);
            hu[1] = f2bf(v0.y);
            hu[2] = f2bf(v0.z);
            hu[3] = f2bf(v0.w);
            hu[4] = f2bf(v1.x);
            hu[5] = f2bf(v1.y);
            hu[6] = f2bf(v1.z);
            hu[7] = f2bf(v1.w);
            ah[tt][kk] = u2b(hu);
        }
    }

    float b1[4][4], b2[4][4];
#pragma unroll
    for (int tt = 0; tt < 4; ++tt)
#pragma unroll
        for (int r = 0; r < 4; ++r) { b1[tt][r] = -3.0e38f; b2[tt][r] = -3.0e38f; }

    // per-lane fragment base: lane l reads byte l*16 of each 1KB block
    const unsigned char* gp =
        (const unsigned char*)cbs + (size_t)split * 524288u +
        (unsigned)lane * 16u;

    const f32x4 zq = {0.f, 0.f, 0.f, 0.f};

#define ISSUE(Q, G)                                                            \
    asm volatile(                                                              \
        "global_load_dwordx4 %0, %8, off\n\t"                                  \
        "global_load_dwordx4 %1, %8, off offset:1024\n\t"                      \
        "global_load_dwordx4 %2, %8, off offset:2048\n\t"                      \
        "global_load_dwordx4 %3, %8, off offset:3072\n\t"                      \
        "global_load_dwordx4 %4, %9, off\n\t"                                  \
        "global_load_dwordx4 %5, %9, off offset:1024\n\t"                      \
        "global_load_dwordx4 %6, %9, off offset:2048\n\t"                      \
        "global_load_dwordx4 %7, %9, off offset:3072"                          \
        : "=&v"(Q##0), "=&v"(Q##1), "=&v"(Q##2), "=&v"(Q##3),                  \
          "=&v"(Q##4), "=&v"(Q##5), "=&v"(Q##6), "=&v"(Q##7)                   \
        : "v"((const void*)(G)), "v"((const void*)((G) + 4096)));

    // Counted wait: with 3 sets, <=24 outstanding; 16 remaining => oldest 8
    // (pair p) retired. sched_barrier(0) blocks MFMA hoisting (rule #18).
#define WAITV16                                                                \
    asm volatile("s_waitcnt vmcnt(16)" ::: "memory");                          \
    __builtin_amdgcn_sched_barrier(0);
#define WAITV0                                                                 \
    asm volatile("s_waitcnt vmcnt(0)" ::: "memory");                           \
    __builtin_amdgcn_sched_barrier(0);

#define COMPUTE(Q, P)                                                          \
    {                                                                          \
        f32x4 aA0, aA1, aA2, aA3, aB0, aB1, aB2, aB3;                          \
        aA0 = MF(ah[0][0], B8(Q##0), zq,  0,0,0);                              \
        aA1 = MF(ah[1][0], B8(Q##0), zq,  0,0,0);                              \
        aA2 = MF(ah[2][0], B8(Q##0), zq,  0,0,0);                              \
        aA3 = MF(ah[3][0], B8(Q##0), zq,  0,0,0);                              \
        aB0 = MF(ah[0][0], B8(Q##4), zq,  0,0,0);                              \
        aB1 = MF(ah[1][0], B8(Q##4), zq,  0,0,0);                              \
        aB2 = MF(ah[2][0], B8(Q##4), zq,  0,0,0);                              \
        aB3 = MF(ah[3][0], B8(Q##4), zq,  0,0,0);                              \
        aA0 = MF(ah[0][1], B8(Q##1), aA0, 0,0,0);                              \
        aA1 = MF(ah[1][1], B8(Q##1), aA1, 0,0,0);                              \
        aA2 = MF(ah[2][1], B8(Q##1), aA2, 0,0,0);                              \
        aA3 = MF(ah[3][1], B8(Q##1), aA3, 0,0,0);                              \
        aB0 = MF(ah[0][1], B8(Q##5), aB0, 0,0,0);                              \
        aB1 = MF(ah[1][1], B8(Q##5), aB1, 0,0,0);                              \
        aB2 = MF(ah[2][1], B8(Q##5), aB2, 0,0,0);                              \
        aB3 = MF(ah[3][1], B8(Q##5), aB3, 0,0,0);                              \
        aA0 = MF(ah[0][2], B8(Q##2), aA0, 0,0,0);                              \
        aA1 = MF(ah[1][2], B8(Q##2), aA1, 0,0,0);                              \
        aA2 = MF(ah[2][2], B8(Q##2), aA2, 0,0,0);                              \
        aA3 = MF(ah[3][2], B8(Q##2), aA3, 0,0,0);                              \
        aB0 = MF(ah[0][2], B8(Q##6), aB0, 0,0,0);                              \
        aB1 = MF(ah[1][2], B8(Q##6), aB1, 0,0,0);                              \
        aB2 = MF(ah[2][2], B8(Q##6), aB2, 0,0,0);                              \
        aB3 = MF(ah[3][2], B8(Q##6), aB3, 0,0,0);                              \
        aA0 = MF(ah[0][3], B8(Q##3), aA0, 0,0,0);                              \
        aA1 = MF(ah[1][3], B8(Q##3), aA1, 0,0,0);                              \
        aA2 = MF(ah[2][3], B8(Q##3), aA2, 0,0,0);                              \
        aA3 = MF(ah[3][3], B8(Q##3), aA3, 0,0,0);                              \
        aB0 = MF(ah[0][3], B8(Q##7), aB0, 0,0,0);                              \
        aB1 = MF(ah[1][3], B8(Q##7), aB1, 0,0,0);                              \
        aB2 = MF(ah[2][3], B8(Q##7), aB2, 0,0,0);                              \
        aB3 = MF(ah[3][3], B8(Q##7), aB3, 0,0,0);                              \
        const unsigned pkA = (unsigned)(127 - (P) * 2);                        \
        const unsigned pkB = (unsigned)(127 - (P) * 2 - 1);                    \
        top2_upd(aA0, b1[0], b2[0], pkA);                                      \
        top2_upd(aA1, b1[1], b2[1], pkA);                                      \
        top2_upd(aA2, b1[2], b2[2], pkA);                                      \
        top2_upd(aA3, b1[3], b2[3], pkA);                                      \
        top2_upd(aB0, b1[0], b2[0], pkB);                                      \
        top2_upd(aB1, b1[1], b2[1], pkB);                                      \
        top2_upd(aB2, b1[2], b2[2], pkB);                                      \
        top2_upd(aB3, b1[3], b2[3], pkB);                                      \
    }

    i32x4 qa0, qa1, qa2, qa3, qa4, qa5, qa6, qa7;
    i32x4 qb0, qb1, qb2, qb3, qb4, qb5, qb6, qb7;
    i32x4 qc0, qc1, qc2, qc3, qc4, qc5, qc6, qc7;

    WAITV0                               // drain A-prologue loads
    ISSUE(qa, gp)                        // pair 0
    ISSUE(qb, gp + 8192)                 // pair 1
    ISSUE(qc, gp + 16384)                // pair 2

    // 21 iterations x 3 pairs = pairs 0..62; issues run to pair 65
    // (over-read of pairs 64/65 lands in mapped sb region -- never computed).
    for (int p = 0; p < 63; p += 3) {
        WAITV16                          // pair p retired; p+1,p+2 in flight
        COMPUTE(qa, p)
        ISSUE(qa, gp + (size_t)(p + 3) * 8192)
        WAITV16
        COMPUTE(qb, p + 1)
        ISSUE(qb, gp + (size_t)(p + 4) * 8192)
        WAITV16
        COMPUTE(qc, p + 2)
        ISSUE(qc, gp + (size_t)(p + 5) * 8192)
    }
    WAITV0                               // pair 63 landed (in qa)
    COMPUTE(qa, 63)

#undef ISSUE
#undef WAITV16
#undef WAITV0
#undef COMPUTE

    // unpack (score, code) and cross-lane top-2 merge over 16 code-lanes
    const int cb_base = split * (NC / NSPLIT);
    float v1[4][4], v2[4][4];
    int   c1[4][4], c2[4][4];
#pragma unroll
    for (int tt = 0; tt < 4; ++tt)
#pragma unroll
        for (int r = 0; r < 4; ++r) {
            int j1 = 127 - (int)(__float_as_uint(b1[tt][r]) & 127u);
            int j2 = 127 - (int)(__float_as_uint(b2[tt][r]) & 127u);
            v1[tt][r] = b1[tt][r]; c1[tt][r] = cb_base + j1 * 16 + n;
            v2[tt][r] = b2[tt][r]; c2[tt][r] = cb_base + j2 * 16 + n;
        }

#pragma unroll
    for (int tt = 0; tt < 4; ++tt)
#pragma unroll
        for (int r = 0; r < 4; ++r) {
#pragma unroll
            for (int off = 1; off < 16; off <<= 1) {
                float ob1 = __shfl_xor(v1[tt][r], off, 64);
                int   oi1 = __shfl_xor(c1[tt][r], off, 64);
                float ob2 = __shfl_xor(v2[tt][r], off, 64);
                int   oi2 = __shfl_xor(c2[tt][r], off, 64);
                bool gt = (ob1 > v1[tt][r]) ||
                          (ob1 == v1[tt][r] && oi1 < c1[tt][r]);
                float ls = gt ? v1[tt][r] : ob1;
                int   li = gt ? c1[tt][r] : oi1;
                float ws_ = gt ? ob2 : v2[tt][r];
                int   wi = gt ? oi2 : c2[tt][r];
                bool s2 = (ls > ws_) || (ls == ws_ && li < wi);
                v2[tt][r] = s2 ? ls : ws_;
                c2[tt][r] = s2 ? li : wi;
                v1[tt][r] = gt ? ob1 : v1[tt][r];
                c1[tt][r] = gt ? oi1 : c1[tt][r];
            }
        }

    // each wave owns its 64 tokens exclusively -> direct store
    if (n == 0) {
#pragma unroll
        for (int tt = 0; tt < 4; ++tt)
#pragma unroll
            for (int r = 0; r < 4; ++r) {
                const int token = t0 + w * 64 + tt * 16 + quad * 4 + r;
                const size_t o = (size_t)split * NT + token;
                sb1[o] = v1[tt][r]; si1[o] = c1[tt][r];
                sb2[o] = v2[tt][r]; si2[o] = c2[tt][r];
            }
    }
}

// ---- combine: wave-cooperative merge + distributed exact rescore ----
__global__ __launch_bounds__(256) void lfq_combine(
    const float* __restrict__ sb1, const float* __restrict__ sb2,
    const int* __restrict__ si1, const int* __restrict__ si2,
    const float* __restrict__ xf, const float* __restrict__ cf,
    float* __restrict__ out, int out_size)
{
    const int lane = threadIdx.x & 63;
    const int wv   = threadIdx.x >> 6;
    const int g    = lane >> 3;        // token sub-index within wave, 0..7
    const int cl   = lane & 7;         // split index, 0..7
    const int t    = (blockIdx.x * 4 + wv) * 8 + g;

    const size_t o = (size_t)cl * NT + t;
    const float va = sb1[o]; const int ia = si1[o];
    const float vb = sb2[o]; const int ib = si2[o];

    // lane-local best (lowest-id tiebreak), then 8-lane group max
    bool lgt = (vb > va) || (vb == va && ib < ia);
    float m  = lgt ? vb : va;
    int   mi = lgt ? ib : ia;
#pragma unroll
    for (int off = 1; off < 8; off <<= 1) {
        float om = __shfl_xor(m, off, 64);
        int   oi = __shfl_xor(mi, off, 64);
        if (om > m || (om == m && oi < mi)) { m = om; mi = oi; }
    }
    const float A1 = m;
    const int   I1 = mi;

    const bool ba = (va >= A1 - MARGIN);
    const bool bb_ = (vb >= A1 - MARGIN);
    int cnt = (ba ? 1 : 0) + (bb_ ? 1 : 0);
#pragma unroll
    for (int off = 1; off < 8; off <<= 1)
        cnt += __shfl_xor(cnt, off, 64);

    int bi = I1;
    if (cnt > 1) {
        float sa = -__builtin_inff(), sb_ = -__builtin_inff();
        if (ba)  sa  = exact_dot_g(xf, cf, t, ia);
        if (bb_) sb_ = exact_dot_g(xf, cf, t, ib);
        bool g2 = (sb_ > sa) || (sb_ == sa && ib < ia);
        float bs = g2 ? sb_ : sa;
        int  bid = g2 ? ib : ia;
#pragma unroll
        for (int off = 1; off < 8; off <<= 1) {
            float os = __shfl_xor(bs, off, 64);
            int   oi = __shfl_xor(bid, off, 64);
            if (os > bs || (os == bs && oi < bid)) { bs = os; bid = oi; }
        }
        bi = bid;
    }
    if (cl == 0) out[t] = (float)bi;
    if (blockIdx.x == 0 && threadIdx.x == 0 && out_size > NT) out[NT] = 0.0f;
}

// ------------- fallback: round-3 exact fp32 kernel (tiny ws) -------------
__global__ __launch_bounds__(512) void lfq_fp32_argmax(
    const float* __restrict__ xf, const float* __restrict__ cf,
    float* __restrict__ out, int out_size)
{
    const int tid = threadIdx.x;
    const int w   = tid >> 6;
    const int tok = tid & 63;
    const int t0  = blockIdx.x * 64;
    __shared__ float s_sc[8][64];
    __shared__ int   s_ix[8][64];

    float4 xr[32];
    const float4* xrow = (const float4*)(xf + (size_t)(t0 + tok) * ND);
#pragma unroll
    for (int i = 0; i < 32; ++i) xr[i] = xrow[i];

    float bs = -__builtin_inff();
    int   bi = 0;
    const int c_begin = w * (NC / 8);
    for (int c = c_begin; c < c_begin + NC / 8; ++c) {
        float s = exact_dot(xr, cf, c);
        if (s > bs) { bs = s; bi = c; }
    }
    s_sc[w][tok] = bs; s_ix[w][tok] = bi;
    __syncthreads();
    if (tid < 64) {
        float bsf = s_sc[0][tid]; int bif = s_ix[0][tid];
#pragma unroll
        for (int ww = 1; ww < 8; ++ww) {
            float s2 = s_sc[ww][tid]; int ii = s_ix[ww][tid];
            if (s2 > bsf || (s2 == bsf && ii < bif)) { bsf = s2; bif = ii; }
        }
        out[t0 + tid] = (float)bif;
    }
    if (blockIdx.x == 0 && tid == 0 && out_size > NT) out[NT] = 0.0f;
}

extern "C" void kernel_launch(void* const* d_in, const int* in_sizes, int n_in,
                              void* d_out, int out_size, void* d_ws, size_t ws_size,
                              hipStream_t stream) {
    const float* x  = (const float*)d_in[0];
    const float* cb = (const float*)d_in[1];
    float* out = (float*)d_out;

    // ws: cbs 4.19MB (fragment-coalesced image) | sb1/sb2/si1/si2 512KB ea
    const size_t NCE = (size_t)NC * ND;          // 2,097,152 codebook elements
    const size_t NEED = NCE * 2 + (size_t)NT * NSPLIT * 4 * 4;
    if (ws_size >= NEED) {
        char* ws = (char*)d_ws;
        unsigned short* cbs = (unsigned short*)ws;
        char* sp = ws + NCE * 2;
        float* sb1 = (float*)sp;
        float* sb2 = (float*)(sp + (size_t)NT * NSPLIT * 4);
        int*   si1 = (int*)  (sp + (size_t)NT * NSPLIT * 8);
        int*   si2 = (int*)  (sp + (size_t)NT * NSPLIT * 12);

        lfq_convert_cb<<<dim3(1024), dim3(256), 0, stream>>>(
            (const float4*)cb, cbs);
        lfq_stage1<<<dim3((NT / 256) * NSPLIT), dim3(256), 0, stream>>>(
            x, cbs, sb1, sb2, si1, si2);
        lfq_combine<<<dim3(NT / 32), dim3(256), 0, stream>>>(
            sb1, sb2, si1, si2, x, cb, out, out_size);
    } else {
        lfq_fp32_argmax<<<dim3(NT / 64), dim3(512), 0, stream>>>(x, cb, out, out_size);
    }
}